// Round 11
// baseline (151.001 us; speedup 1.0000x reference)
//
#include <hip/hip_runtime.h>

#define BC 16
#define NN 2048
#define FF 128
#define DD 128
#define NEDGES 65536
#define NEG_INF -1e16f
#define LEAK 0.1f
#define CAPR 128   // per-row in-degree cap; P(Poisson(32) > 128) ~ 1e-35
#define THRS 20.0f // defer-max: exp(20)=4.9e8; scale cancels at normalize (verified R4-R9)

// ---------------- Kernel 1 (fused): edge atomicOr + z = h @ W ------------
// byte-identical to the R8-verified kernel (best total: 142.9 us).
// blocks 0..255: adjacency bits; blocks 256..1279: zgemm with W in LDS.
__global__ void __launch_bounds__(256) zedge_kernel(const float* __restrict__ h,
                                                    const float* __restrict__ W,
                                                    float* __restrict__ z,
                                                    const int* __restrict__ row,
                                                    const int* __restrict__ col,
                                                    unsigned int* __restrict__ mask) {
    __shared__ float W_lds[FF][DD];   // 64 KB
    __shared__ float hs[32][FF];      // 16 KB  (80 KB total -> 2 blocks/CU)
    const int tid = threadIdx.x;
    const int blk = blockIdx.x;

    if (blk < 256) {   // ---- edge part
        const int e = blk * 256 + tid;
        const unsigned int key = (unsigned int)row[e] * NN + (unsigned int)col[e];
        atomicOr(&mask[key >> 5], 1u << (key & 31u));
        return;
    }

    // ---- stage W (16 float4/thread) and the 32-row h tile (4 float4/thread)
    {
        const float4* wg = (const float4*)W;
        float4* wl = (float4*)&W_lds[0][0];
#pragma unroll
        for (int i = 0; i < 16; ++i) wl[tid + 256 * i] = wg[tid + 256 * i];
        const size_t row0 = (size_t)(blk - 256) * 32;
        const float4* hv = (const float4*)(h + row0 * FF);
        float4* hsv = (float4*)&hs[0][0];
#pragma unroll
        for (int i = 0; i < 4; ++i) hsv[tid + 256 * i] = hv[tid + 256 * i];
    }
    __syncthreads();

    const size_t row0 = (size_t)(blk - 256) * 32;
    const int c0 = (tid & 31) * 4;
    const int r0 = (tid >> 5) * 4;
    float acc[4][4] = {};
#pragma unroll 2
    for (int f = 0; f < FF; f += 4) {
        float4 a[4], bb[4];
#pragma unroll
        for (int r = 0; r < 4; ++r) a[r] = *(const float4*)&hs[r0 + r][f];
#pragma unroll
        for (int k = 0; k < 4; ++k) bb[k] = *(const float4*)&W_lds[f + k][c0];
#pragma unroll
        for (int r = 0; r < 4; ++r) {
            acc[r][0] += a[r].x * bb[0].x + a[r].y * bb[1].x + a[r].z * bb[2].x + a[r].w * bb[3].x;
            acc[r][1] += a[r].x * bb[0].y + a[r].y * bb[1].y + a[r].z * bb[2].y + a[r].w * bb[3].y;
            acc[r][2] += a[r].x * bb[0].z + a[r].y * bb[1].z + a[r].z * bb[2].z + a[r].w * bb[3].z;
            acc[r][3] += a[r].x * bb[0].w + a[r].y * bb[1].w + a[r].z * bb[2].w + a[r].w * bb[3].w;
        }
    }
#pragma unroll
    for (int r = 0; r < 4; ++r)
        *(float4*)&z[(row0 + r0 + r) * DD + c0] =
            make_float4(acc[r][0], acc[r][1], acc[r][2], acc[r][3]);
}

// ---------------- Kernel 2: gat batch-half (R6-verified loop) ------------
// Processes b in [b0, b0+8) over all 2048 rows: 16384 wave-tasks ->
// grid MUST be 4096 blocks x 4 waves (R10 launched 2048: rows 1024+
// were never written -> correctness failure).
__global__ void __launch_bounds__(256) gat_kernel(const float* __restrict__ z,
                                                  const unsigned int* __restrict__ mask,
                                                  float* __restrict__ out,
                                                  int b0) {
    __shared__ unsigned short hits_l[4][CAPR];   // 1 KB, one row per wave
    const int tid = threadIdx.x, wv = tid >> 6, ln = tid & 63;
    const int blk = blockIdx.x;
    const int b = b0 | (((blk & 3) << 1) | (wv & 1));   // b0 in {0,8}
    const int n = ((blk >> 2) << 1) | (wv >> 1);        // [0,2048) with 4096 blocks
    const int eq = ln >> 3, hq = ln & 7;

    // ---- in-wave CSR decode (wave-private LDS; same-wave DS ordering)
    unsigned int bits = mask[n * 64 + ln];
    const int cnt = __popc(bits);
    int pre = cnt;
#pragma unroll
    for (int off = 1; off <= 32; off <<= 1) {
        const int t = __shfl_up(pre, off, 64);
        if (ln >= off) pre += t;
    }
    const int total = __shfl(pre, 63, 64);   // inclusive total = row degree
    int slot = pre - cnt;                    // exclusive prefix = lane's base
    while (bits) {
        const int bit = __ffs(bits) - 1;
        bits &= bits - 1;
        if (slot < CAPR) hits_l[wv][slot] = (unsigned short)(ln * 32 + bit);
        ++slot;
    }
    const int nh = min(total, CAPR);
    const int hv0 = hits_l[wv][ln];          // edges 0..63
    const int hv1 = hits_l[wv][64 + ln];     // edges 64..127

    const float* zb = z + ((size_t)b << 18);   // b*2048*128
    const float4* znp = (const float4*)(zb + ((size_t)n << 7) + (hq << 4));
    const float4 a0 = znp[0], a1 = znp[1], a2 = znp[2], a3 = znp[3];

    float m = NEG_INF, l = 0.f;
    float4 acc0 = make_float4(0.f, 0.f, 0.f, 0.f), acc1 = acc0, acc2 = acc0, acc3 = acc0;

#pragma unroll 2
    for (int c0 = 0; c0 < nh; c0 += 8) {
        const int e = c0 + eq;
        const int hv = (c0 < 64) ? hv0 : hv1;      // uniform select (c0 loop-scalar)
        const int he = __shfl(hv, e & 63, 64) & (NN - 1);   // edge id from registers
        const float4* zc = (const float4*)(zb + ((size_t)he << 7) + (hq << 4));
        const float4 v0 = zc[0], v1 = zc[1], v2 = zc[2], v3 = zc[3];
        float ch0 = a0.x * v0.x + a0.y * v0.y + a0.z * v0.z + a0.w * v0.w
                  + a1.x * v1.x + a1.y * v1.y + a1.z * v1.z + a1.w * v1.w;
        float ch1 = a2.x * v2.x + a2.y * v2.y + a2.z * v2.z + a2.w * v2.w
                  + a3.x * v3.x + a3.y * v3.y + a3.z * v3.z + a3.w * v3.w;
        float pt = ch0 + ch1;
        pt += __shfl_xor(pt, 1, 64);
        pt += __shfl_xor(pt, 2, 64);
        pt += __shfl_xor(pt, 4, 64);             // full 128-dim dot in all hq lanes
        float sv = pt > 0.f ? pt : LEAK * pt;    // leaky_relu(0.1)
        if (sv == 0.f || e >= nh) sv = NEG_INF;  // masked_fill(att==0) / pad

        if (__any(sv - m > THRS)) {              // defer-max rescale (rare)
            const float mnew = fmaxf(m, sv);
            const float alpha = __expf(m - mnew);
            m = mnew;
            l *= alpha;
            acc0.x *= alpha; acc0.y *= alpha; acc0.z *= alpha; acc0.w *= alpha;
            acc1.x *= alpha; acc1.y *= alpha; acc1.z *= alpha; acc1.w *= alpha;
            acc2.x *= alpha; acc2.y *= alpha; acc2.z *= alpha; acc2.w *= alpha;
            acc3.x *= alpha; acc3.y *= alpha; acc3.z *= alpha; acc3.w *= alpha;
        }
        const float pr = __expf(sv - m);         // exponent <= THRS, fp32-safe
        l += pr;
        acc0.x += pr * v0.x; acc0.y += pr * v0.y; acc0.z += pr * v0.z; acc0.w += pr * v0.w;
        acc1.x += pr * v1.x; acc1.y += pr * v1.y; acc1.z += pr * v1.z; acc1.w += pr * v1.w;
        acc2.x += pr * v2.x; acc2.y += pr * v2.y; acc2.z += pr * v2.z; acc2.w += pr * v2.w;
        acc3.x += pr * v3.x; acc3.y += pr * v3.y; acc3.z += pr * v3.z; acc3.w += pr * v3.w;
    }

    float M = m;
#pragma unroll
    for (int off = 8; off <= 32; off <<= 1) M = fmaxf(M, __shfl_xor(M, off, 64));

    if (nh > 0 && M > 0.5f * NEG_INF) {
        const float al = __expf(m - M);          // 0 for all-pad lanes
        l *= al;
        acc0.x *= al; acc0.y *= al; acc0.z *= al; acc0.w *= al;
        acc1.x *= al; acc1.y *= al; acc1.z *= al; acc1.w *= al;
        acc2.x *= al; acc2.y *= al; acc2.z *= al; acc2.w *= al;
        acc3.x *= al; acc3.y *= al; acc3.z *= al; acc3.w *= al;
#pragma unroll
        for (int off = 8; off <= 32; off <<= 1) {
            l += __shfl_xor(l, off, 64);
            acc0.x += __shfl_xor(acc0.x, off, 64); acc0.y += __shfl_xor(acc0.y, off, 64);
            acc0.z += __shfl_xor(acc0.z, off, 64); acc0.w += __shfl_xor(acc0.w, off, 64);
            acc1.x += __shfl_xor(acc1.x, off, 64); acc1.y += __shfl_xor(acc1.y, off, 64);
            acc1.z += __shfl_xor(acc1.z, off, 64); acc1.w += __shfl_xor(acc1.w, off, 64);
            acc2.x += __shfl_xor(acc2.x, off, 64); acc2.y += __shfl_xor(acc2.y, off, 64);
            acc2.z += __shfl_xor(acc2.z, off, 64); acc2.w += __shfl_xor(acc2.w, off, 64);
            acc3.x += __shfl_xor(acc3.x, off, 64); acc3.y += __shfl_xor(acc3.y, off, 64);
            acc3.z += __shfl_xor(acc3.z, off, 64); acc3.w += __shfl_xor(acc3.w, off, 64);
        }
        const float inv = 1.f / l;
        acc0.x *= inv; acc0.y *= inv; acc0.z *= inv; acc0.w *= inv;
        acc1.x *= inv; acc1.y *= inv; acc1.z *= inv; acc1.w *= inv;
        acc2.x *= inv; acc2.y *= inv; acc2.z *= inv; acc2.w *= inv;
        acc3.x *= inv; acc3.y *= inv; acc3.z *= inv; acc3.w *= inv;
    } else {
        // no valid edge: softmax over uniform -1e16 row -> mean of z[b]
        acc0 = make_float4(0.f, 0.f, 0.f, 0.f); acc1 = acc0; acc2 = acc0; acc3 = acc0;
        for (int mm = 0; mm < NN; ++mm) {
            const float4* zr = (const float4*)(zb + ((size_t)mm << 7) + (hq << 4));
            const float4 t0 = zr[0], t1 = zr[1], t2 = zr[2], t3 = zr[3];
            acc0.x += t0.x; acc0.y += t0.y; acc0.z += t0.z; acc0.w += t0.w;
            acc1.x += t1.x; acc1.y += t1.y; acc1.z += t1.z; acc1.w += t1.w;
            acc2.x += t2.x; acc2.y += t2.y; acc2.z += t2.z; acc2.w += t2.w;
            acc3.x += t3.x; acc3.y += t3.y; acc3.z += t3.z; acc3.w += t3.w;
        }
        const float s = 1.f / NN;
        acc0.x *= s; acc0.y *= s; acc0.z *= s; acc0.w *= s;
        acc1.x *= s; acc1.y *= s; acc1.z *= s; acc1.w *= s;
        acc2.x *= s; acc2.y *= s; acc2.z *= s; acc2.w *= s;
        acc3.x *= s; acc3.y *= s; acc3.z *= s; acc3.w *= s;
    }

    if (eq < 4) {
        float4 o = acc0;
        if (eq == 1) o = acc1;
        if (eq == 2) o = acc2;
        if (eq == 3) o = acc3;
        *(float4*)(out + (((size_t)b * NN + n) << 7) + (hq << 4) + (eq << 2)) = o;
    }
}

// ---------------- launcher ----------------
extern "C" void kernel_launch(void* const* d_in, const int* in_sizes, int n_in,
                              void* d_out, int out_size, void* d_ws, size_t ws_size,
                              hipStream_t stream) {
    const float* h = (const float*)d_in[0];
    const float* W = (const float*)d_in[1];
    const int* row = (const int*)d_in[2];
    const int* col = (const int*)d_in[3];
    float* out = (float*)d_out;

    char* ws = (char*)d_ws;
    float* z = (float*)ws;                                                 // 16 MB
    unsigned int* mask = (unsigned int*)(ws + (size_t)16 * 1024 * 1024);   // 512 KB

    hipMemsetAsync(mask, 0, (size_t)NN * NN / 8, stream);
    zedge_kernel<<<1280, 256, 0, stream>>>(h, W, z, row, col, mask);
    // 16384 wave-tasks per half -> 4096 blocks x 4 waves (grid = tasks/4)
    gat_kernel<<<(BC * NN) / 8, 256, 0, stream>>>(z, mask, out, 0);
    gat_kernel<<<(BC * NN) / 8, 256, 0, stream>>>(z, mask, out, 8);
}

// Round 13
// 144.602 us; speedup vs baseline: 1.0443x; 1.0443x over previous
//
#include <hip/hip_runtime.h>

#define BC 16
#define NN 2048
#define FF 128
#define DD 128
#define NEDGES 65536
#define NEG_INF -1e16f
#define LEAK 0.1f
#define CAPR 128   // per-row in-degree cap; P(Poisson(32) > 128) ~ 1e-35
#define THRS 20.0f // defer-max: exp(20)=4.9e8; scale cancels at normalize (verified R4-R9)

typedef __attribute__((ext_vector_type(8))) short s16x8;   // 8 bf16 (4 VGPRs)
typedef __attribute__((ext_vector_type(4))) float f32x4;   // MFMA accumulator

__device__ __forceinline__ unsigned short f2bf(float x) {  // fp32 -> bf16 RTN-even
    const unsigned int u = __float_as_uint(x);
    return (unsigned short)((u + 0x7FFFu + ((u >> 16) & 1u)) >> 16);
}
__device__ __forceinline__ float bf2f(unsigned short b) {
    return __uint_as_float(((unsigned int)b) << 16);
}

// ---------------- Kernel 1 (fused): edge atomicOr + z = h @ W ------------
// bf16x3 split MFMA GEMM: x = hi + lo (two bf16); z = hi*hi + lo*hi + hi*lo
// (lo*lo ~ 2^-16 relative, dropped). bf16 products are exact in the fp32
// MFMA accumulator -> z error ~2e-4 abs (R12's plain-bf16 absmax 0.64 was
// precision, not layout: structural bugs fail at O(5), cf. R10's 468).
// blocks 0..255: adjacency bits. blocks 256..767: one 64-row z tile each.
__global__ void __launch_bounds__(256) zedge_kernel(const float* __restrict__ h,
                                                    const float* __restrict__ W,
                                                    float* __restrict__ z,
                                                    const int* __restrict__ row,
                                                    const int* __restrict__ col,
                                                    unsigned int* __restrict__ mask) {
    // W transposed to bf16, rows of 512 B: [ hi k=0..127 | lo k=0..127 ] per d.
    // XOR-swizzle on the 16B-chunk index within each half: chunk ^= (d&7).
    __shared__ unsigned short Wb[FF * DD * 2];   // 64 KB
    const int tid = threadIdx.x;
    const int blk = blockIdx.x;

    if (blk < 256) {   // ---- edge part
        const int e = blk * 256 + tid;
        const unsigned int key = (unsigned int)row[e] * NN + (unsigned int)col[e];
        atomicOr(&mask[key >> 5], 1u << (key & 31u));
        return;
    }

    // ---- transpose-split-convert W[k][d] fp32 -> Wb[d][{hi,lo}][k] (swizzled)
    {
        const float4* wg = (const float4*)W;   // 4096 float4
#pragma unroll
        for (int j = 0; j < 16; ++j) {
            const int idx = tid + 256 * j;
            const float4 v = wg[idx];
            const int k = idx >> 5;             // W row (= gemm K index)
            const int d0 = (idx & 31) << 2;     // 4 consecutive d
            const int kb = k * 2;
            const int base = kb & ~15, within = kb & 15;
            const float vv[4] = {v.x, v.y, v.z, v.w};
#pragma unroll
            for (int c = 0; c < 4; ++c) {
                const int d = d0 + c;
                const unsigned short hi = f2bf(vv[c]);
                const unsigned short lo = f2bf(vv[c] - bf2f(hi));
                const int off = d * 512 + ((base ^ ((d & 7) << 4)) | within);
                Wb[off >> 1] = hi;
                Wb[(off + 256) >> 1] = lo;
            }
        }
    }
    __syncthreads();

    const int ln = tid & 63, wv = tid >> 6;
    const int m0 = (blk - 256) * 64 + wv * 16;   // 512 blocks x 64 rows = 32768
    const int mr = m0 + (ln & 15);               // A-frag row
    const int koct = (ln >> 4) * 8;              // A/B k-octet base

    // ---- A-frags hi/lo: 8 consecutive k per lane per k0, split in-register
    s16x8 ah[4], al[4];
#pragma unroll
    for (int k0 = 0; k0 < 4; ++k0) {
        const float* hp = h + (size_t)mr * FF + k0 * 32 + koct;
        const float4 p = *(const float4*)hp;
        const float4 q = *(const float4*)(hp + 4);
        const float x[8] = {p.x, p.y, p.z, p.w, q.x, q.y, q.z, q.w};
        s16x8 hi8, lo8;
#pragma unroll
        for (int i = 0; i < 8; ++i) {
            const unsigned short hb = f2bf(x[i]);
            hi8[i] = (short)hb;
            lo8[i] = (short)f2bf(x[i] - bf2f(hb));
        }
        ah[k0] = hi8; al[k0] = lo8;
    }

    f32x4 acc[8] = {};   // 8 d-tiles x 4 f32 (static indexing everywhere)
#pragma unroll
    for (int k0 = 0; k0 < 4; ++k0) {
#pragma unroll
        for (int dt = 0; dt < 8; ++dt) {
            const int d = dt * 16 + (ln & 15);          // B-frag col
            const int kb = (k0 * 32 + koct) * 2;        // 16B-aligned
            const int off = d * 512 + (kb ^ ((d & 7) << 4));
            const s16x8 bh = *(const s16x8*)((const char*)Wb + off);
            const s16x8 bl = *(const s16x8*)((const char*)Wb + off + 256);
            acc[dt] = __builtin_amdgcn_mfma_f32_16x16x32_bf16(ah[k0], bh, acc[dt], 0, 0, 0);
            acc[dt] = __builtin_amdgcn_mfma_f32_16x16x32_bf16(al[k0], bh, acc[dt], 0, 0, 0);
            acc[dt] = __builtin_amdgcn_mfma_f32_16x16x32_bf16(ah[k0], bl, acc[dt], 0, 0, 0);
        }
    }

    // ---- store: D col = lane&15, row = (lane>>4)*4 + reg (m89/m91 mapping)
    const int dcol = ln & 15;
    const int rbase = m0 + (ln >> 4) * 4;
#pragma unroll
    for (int dt = 0; dt < 8; ++dt)
#pragma unroll
        for (int r = 0; r < 4; ++r)
            z[(size_t)(rbase + r) * DD + dt * 16 + dcol] = acc[dt][r];
}

// ---------------- Kernel 2: gat, single dispatch (R6-verified 57.5 us) ---
__global__ void __launch_bounds__(256) gat_kernel(const float* __restrict__ z,
                                                  const unsigned int* __restrict__ mask,
                                                  float* __restrict__ out) {
    __shared__ unsigned short hits_l[4][CAPR];   // 1 KB, one row per wave
    const int tid = threadIdx.x, wv = tid >> 6, ln = tid & 63;
    const int blk = blockIdx.x;
    const int b = ((blk & 7) << 1) | (wv & 1);
    const int n = ((blk >> 3) << 1) | (wv >> 1);
    const int eq = ln >> 3, hq = ln & 7;

    // ---- in-wave CSR decode (wave-private LDS; same-wave DS ordering)
    unsigned int bits = mask[n * 64 + ln];
    const int cnt = __popc(bits);
    int pre = cnt;
#pragma unroll
    for (int off = 1; off <= 32; off <<= 1) {
        const int t = __shfl_up(pre, off, 64);
        if (ln >= off) pre += t;
    }
    const int total = __shfl(pre, 63, 64);   // inclusive total = row degree
    int slot = pre - cnt;                    // exclusive prefix = lane's base
    while (bits) {
        const int bit = __ffs(bits) - 1;
        bits &= bits - 1;
        if (slot < CAPR) hits_l[wv][slot] = (unsigned short)(ln * 32 + bit);
        ++slot;
    }
    const int nh = min(total, CAPR);
    const int hv0 = hits_l[wv][ln];          // edges 0..63
    const int hv1 = hits_l[wv][64 + ln];     // edges 64..127

    const float* zb = z + ((size_t)b << 18);   // b*2048*128
    const float4* znp = (const float4*)(zb + ((size_t)n << 7) + (hq << 4));
    const float4 a0 = znp[0], a1 = znp[1], a2 = znp[2], a3 = znp[3];

    float m = NEG_INF, l = 0.f;
    float4 acc0 = make_float4(0.f, 0.f, 0.f, 0.f), acc1 = acc0, acc2 = acc0, acc3 = acc0;

#pragma unroll 2
    for (int c0 = 0; c0 < nh; c0 += 8) {
        const int e = c0 + eq;
        const int hv = (c0 < 64) ? hv0 : hv1;      // uniform select (c0 loop-scalar)
        const int he = __shfl(hv, e & 63, 64) & (NN - 1);   // edge id from registers
        const float4* zc = (const float4*)(zb + ((size_t)he << 7) + (hq << 4));
        const float4 v0 = zc[0], v1 = zc[1], v2 = zc[2], v3 = zc[3];
        float ch0 = a0.x * v0.x + a0.y * v0.y + a0.z * v0.z + a0.w * v0.w
                  + a1.x * v1.x + a1.y * v1.y + a1.z * v1.z + a1.w * v1.w;
        float ch1 = a2.x * v2.x + a2.y * v2.y + a2.z * v2.z + a2.w * v2.w
                  + a3.x * v3.x + a3.y * v3.y + a3.z * v3.z + a3.w * v3.w;
        float pt = ch0 + ch1;
        pt += __shfl_xor(pt, 1, 64);
        pt += __shfl_xor(pt, 2, 64);
        pt += __shfl_xor(pt, 4, 64);             // full 128-dim dot in all hq lanes
        float sv = pt > 0.f ? pt : LEAK * pt;    // leaky_relu(0.1)
        if (sv == 0.f || e >= nh) sv = NEG_INF;  // masked_fill(att==0) / pad

        if (__any(sv - m > THRS)) {              // defer-max rescale (rare)
            const float mnew = fmaxf(m, sv);
            const float alpha = __expf(m - mnew);
            m = mnew;
            l *= alpha;
            acc0.x *= alpha; acc0.y *= alpha; acc0.z *= alpha; acc0.w *= alpha;
            acc1.x *= alpha; acc1.y *= alpha; acc1.z *= alpha; acc1.w *= alpha;
            acc2.x *= alpha; acc2.y *= alpha; acc2.z *= alpha; acc2.w *= alpha;
            acc3.x *= alpha; acc3.y *= alpha; acc3.z *= alpha; acc3.w *= alpha;
        }
        const float pr = __expf(sv - m);         // exponent <= THRS, fp32-safe
        l += pr;
        acc0.x += pr * v0.x; acc0.y += pr * v0.y; acc0.z += pr * v0.z; acc0.w += pr * v0.w;
        acc1.x += pr * v1.x; acc1.y += pr * v1.y; acc1.z += pr * v1.z; acc1.w += pr * v1.w;
        acc2.x += pr * v2.x; acc2.y += pr * v2.y; acc2.z += pr * v2.z; acc2.w += pr * v2.w;
        acc3.x += pr * v3.x; acc3.y += pr * v3.y; acc3.z += pr * v3.z; acc3.w += pr * v3.w;
    }

    float M = m;
#pragma unroll
    for (int off = 8; off <= 32; off <<= 1) M = fmaxf(M, __shfl_xor(M, off, 64));

    if (nh > 0 && M > 0.5f * NEG_INF) {
        const float al = __expf(m - M);          // 0 for all-pad lanes
        l *= al;
        acc0.x *= al; acc0.y *= al; acc0.z *= al; acc0.w *= al;
        acc1.x *= al; acc1.y *= al; acc1.z *= al; acc1.w *= al;
        acc2.x *= al; acc2.y *= al; acc2.z *= al; acc2.w *= al;
        acc3.x *= al; acc3.y *= al; acc3.z *= al; acc3.w *= al;
#pragma unroll
        for (int off = 8; off <= 32; off <<= 1) {
            l += __shfl_xor(l, off, 64);
            acc0.x += __shfl_xor(acc0.x, off, 64); acc0.y += __shfl_xor(acc0.y, off, 64);
            acc0.z += __shfl_xor(acc0.z, off, 64); acc0.w += __shfl_xor(acc0.w, off, 64);
            acc1.x += __shfl_xor(acc1.x, off, 64); acc1.y += __shfl_xor(acc1.y, off, 64);
            acc1.z += __shfl_xor(acc1.z, off, 64); acc1.w += __shfl_xor(acc1.w, off, 64);
            acc2.x += __shfl_xor(acc2.x, off, 64); acc2.y += __shfl_xor(acc2.y, off, 64);
            acc2.z += __shfl_xor(acc2.z, off, 64); acc2.w += __shfl_xor(acc2.w, off, 64);
            acc3.x += __shfl_xor(acc3.x, off, 64); acc3.y += __shfl_xor(acc3.y, off, 64);
            acc3.z += __shfl_xor(acc3.z, off, 64); acc3.w += __shfl_xor(acc3.w, off, 64);
        }
        const float inv = 1.f / l;
        acc0.x *= inv; acc0.y *= inv; acc0.z *= inv; acc0.w *= inv;
        acc1.x *= inv; acc1.y *= inv; acc1.z *= inv; acc1.w *= inv;
        acc2.x *= inv; acc2.y *= inv; acc2.z *= inv; acc2.w *= inv;
        acc3.x *= inv; acc3.y *= inv; acc3.z *= inv; acc3.w *= inv;
    } else {
        // no valid edge: softmax over uniform -1e16 row -> mean of z[b]
        acc0 = make_float4(0.f, 0.f, 0.f, 0.f); acc1 = acc0; acc2 = acc0; acc3 = acc0;
        for (int mm = 0; mm < NN; ++mm) {
            const float4* zr = (const float4*)(zb + ((size_t)mm << 7) + (hq << 4));
            const float4 t0 = zr[0], t1 = zr[1], t2 = zr[2], t3 = zr[3];
            acc0.x += t0.x; acc0.y += t0.y; acc0.z += t0.z; acc0.w += t0.w;
            acc1.x += t1.x; acc1.y += t1.y; acc1.z += t1.z; acc1.w += t1.w;
            acc2.x += t2.x; acc2.y += t2.y; acc2.z += t2.z; acc2.w += t2.w;
            acc3.x += t3.x; acc3.y += t3.y; acc3.z += t3.z; acc3.w += t3.w;
        }
        const float s = 1.f / NN;
        acc0.x *= s; acc0.y *= s; acc0.z *= s; acc0.w *= s;
        acc1.x *= s; acc1.y *= s; acc1.z *= s; acc1.w *= s;
        acc2.x *= s; acc2.y *= s; acc2.z *= s; acc2.w *= s;
        acc3.x *= s; acc3.y *= s; acc3.z *= s; acc3.w *= s;
    }

    if (eq < 4) {
        float4 o = acc0;
        if (eq == 1) o = acc1;
        if (eq == 2) o = acc2;
        if (eq == 3) o = acc3;
        *(float4*)(out + (((size_t)b * NN + n) << 7) + (hq << 4) + (eq << 2)) = o;
    }
}

// ---------------- launcher ----------------
extern "C" void kernel_launch(void* const* d_in, const int* in_sizes, int n_in,
                              void* d_out, int out_size, void* d_ws, size_t ws_size,
                              hipStream_t stream) {
    const float* h = (const float*)d_in[0];
    const float* W = (const float*)d_in[1];
    const int* row = (const int*)d_in[2];
    const int* col = (const int*)d_in[3];
    float* out = (float*)d_out;

    char* ws = (char*)d_ws;
    float* z = (float*)ws;                                                 // 16 MB
    unsigned int* mask = (unsigned int*)(ws + (size_t)16 * 1024 * 1024);   // 512 KB

    hipMemsetAsync(mask, 0, (size_t)NN * NN / 8, stream);
    zedge_kernel<<<768, 256, 0, stream>>>(h, W, z, row, col, mask);   // 256 edge + 512 gemm
    gat_kernel<<<(BC * NN) / 4, 256, 0, stream>>>(z, mask, out);
}

// Round 14
// 136.264 us; speedup vs baseline: 1.1081x; 1.0612x over previous
//
#include <hip/hip_runtime.h>

#define BC 16
#define NN 2048
#define FF 128
#define DD 128
#define NEDGES 65536
#define NEG_INF -1e16f
#define LEAK 0.1f
#define CAPR 128   // per-row in-degree cap; P(Poisson(32) > 128) ~ 1e-35
#define THRS 20.0f // defer-max: exp(20)=4.9e8; scale cancels at normalize (verified R4-R13)

typedef __attribute__((ext_vector_type(8))) short s16x8;   // 8 bf16 (4 VGPRs)
typedef __attribute__((ext_vector_type(4))) float f32x4;   // MFMA accumulator

__device__ __forceinline__ unsigned short f2bf(float x) {  // fp32 -> bf16 RTN-even
    const unsigned int u = __float_as_uint(x);
    return (unsigned short)((u + 0x7FFFu + ((u >> 16) & 1u)) >> 16);
}
__device__ __forceinline__ float bf2f(unsigned short b) {
    return __uint_as_float(((unsigned int)b) << 16);
}

// ---------------- Kernel 0: W prep (once per launch, ~2 us) --------------
// Transpose-split-convert W[k][d] fp32 -> Wp[d][{hi,lo}][k] bf16 with the
// R13-verified XOR swizzle, written to GLOBAL. R13 did this per-GEMM-block
// into LDS with 128 scalar b16 writes/thread all landing on bank 0
// (d*512 stride -> 64-lane single-bank pileup, ~20 us/block-round). Hoisting
// it here makes the GEMM's staging a linear conflict-free copy.
__global__ void __launch_bounds__(256) wprep_kernel(const float* __restrict__ W,
                                                    unsigned short* __restrict__ Wp) {
    const int idx = blockIdx.x * 256 + threadIdx.x;   // 16 blocks -> 4096 float4
    const float4 v = ((const float4*)W)[idx];
    const int k = idx >> 5;             // W row (= gemm K index)
    const int d0 = (idx & 31) << 2;     // 4 consecutive d
    const int kb = k * 2;
    const int base = kb & ~15, within = kb & 15;
    const float vv[4] = {v.x, v.y, v.z, v.w};
#pragma unroll
    for (int c = 0; c < 4; ++c) {
        const int d = d0 + c;
        const unsigned short hi = f2bf(vv[c]);
        const unsigned short lo = f2bf(vv[c] - bf2f(hi));
        const int off = d * 512 + ((base ^ ((d & 7) << 4)) | within);
        Wp[off >> 1] = hi;
        Wp[(off + 256) >> 1] = lo;
    }
}

// ---------------- Kernel 1 (fused): edge atomicOr + z = h @ W ------------
// bf16x3 split MFMA GEMM (R13-verified numerics: absmax 0.03125).
// blocks 0..255: adjacency bits. blocks 256..767: one 64-row z tile each.
// Staging is now a LINEAR 64 KB copy of the pre-swizzled Wp image; frag
// reads / MFMA order / D-store are byte-identical to R13.
__global__ void __launch_bounds__(256) zedge_kernel(const float* __restrict__ h,
                                                    const unsigned short* __restrict__ Wp,
                                                    float* __restrict__ z,
                                                    const int* __restrict__ row,
                                                    const int* __restrict__ col,
                                                    unsigned int* __restrict__ mask) {
    __shared__ unsigned short Wb[FF * DD * 2];   // 64 KB, same byte layout as Wp
    const int tid = threadIdx.x;
    const int blk = blockIdx.x;

    if (blk < 256) {   // ---- edge part
        const int e = blk * 256 + tid;
        const unsigned int key = (unsigned int)row[e] * NN + (unsigned int)col[e];
        atomicOr(&mask[key >> 5], 1u << (key & 31u));
        return;
    }

    // ---- stage Wp linearly: coalesced global float4 + conflict-free b128 writes
    {
        const float4* wg = (const float4*)Wp;   // 4096 float4
        float4* wl = (float4*)Wb;
#pragma unroll
        for (int i = 0; i < 16; ++i) wl[tid + 256 * i] = wg[tid + 256 * i];
    }
    __syncthreads();

    const int ln = tid & 63, wv = tid >> 6;
    const int m0 = (blk - 256) * 64 + wv * 16;   // 512 blocks x 64 rows = 32768
    const int mr = m0 + (ln & 15);               // A-frag row
    const int koct = (ln >> 4) * 8;              // A/B k-octet base

    // ---- A-frags hi/lo: 8 consecutive k per lane per k0, split in-register
    s16x8 ah[4], al[4];
#pragma unroll
    for (int k0 = 0; k0 < 4; ++k0) {
        const float* hp = h + (size_t)mr * FF + k0 * 32 + koct;
        const float4 p = *(const float4*)hp;
        const float4 q = *(const float4*)(hp + 4);
        const float x[8] = {p.x, p.y, p.z, p.w, q.x, q.y, q.z, q.w};
        s16x8 hi8, lo8;
#pragma unroll
        for (int i = 0; i < 8; ++i) {
            const unsigned short hb = f2bf(x[i]);
            hi8[i] = (short)hb;
            lo8[i] = (short)f2bf(x[i] - bf2f(hb));
        }
        ah[k0] = hi8; al[k0] = lo8;
    }

    f32x4 acc[8] = {};   // 8 d-tiles x 4 f32 (static indexing everywhere)
#pragma unroll
    for (int k0 = 0; k0 < 4; ++k0) {
#pragma unroll
        for (int dt = 0; dt < 8; ++dt) {
            const int d = dt * 16 + (ln & 15);          // B-frag col
            const int kb = (k0 * 32 + koct) * 2;        // 16B-aligned
            const int off = d * 512 + (kb ^ ((d & 7) << 4));
            const s16x8 bh = *(const s16x8*)((const char*)Wb + off);
            const s16x8 bl = *(const s16x8*)((const char*)Wb + off + 256);
            acc[dt] = __builtin_amdgcn_mfma_f32_16x16x32_bf16(ah[k0], bh, acc[dt], 0, 0, 0);
            acc[dt] = __builtin_amdgcn_mfma_f32_16x16x32_bf16(al[k0], bh, acc[dt], 0, 0, 0);
            acc[dt] = __builtin_amdgcn_mfma_f32_16x16x32_bf16(ah[k0], bl, acc[dt], 0, 0, 0);
        }
    }

    // ---- store: D col = lane&15, row = (lane>>4)*4 + reg (m89/m91 mapping)
    const int dcol = ln & 15;
    const int rbase = m0 + (ln >> 4) * 4;
#pragma unroll
    for (int dt = 0; dt < 8; ++dt)
#pragma unroll
        for (int r = 0; r < 4; ++r)
            z[(size_t)(rbase + r) * DD + dt * 16 + dcol] = acc[dt][r];
}

// ---------------- Kernel 2: gat, single dispatch (R6-verified 57.5 us) ---
__global__ void __launch_bounds__(256) gat_kernel(const float* __restrict__ z,
                                                  const unsigned int* __restrict__ mask,
                                                  float* __restrict__ out) {
    __shared__ unsigned short hits_l[4][CAPR];   // 1 KB, one row per wave
    const int tid = threadIdx.x, wv = tid >> 6, ln = tid & 63;
    const int blk = blockIdx.x;
    const int b = ((blk & 7) << 1) | (wv & 1);
    const int n = ((blk >> 3) << 1) | (wv >> 1);
    const int eq = ln >> 3, hq = ln & 7;

    // ---- in-wave CSR decode (wave-private LDS; same-wave DS ordering)
    unsigned int bits = mask[n * 64 + ln];
    const int cnt = __popc(bits);
    int pre = cnt;
#pragma unroll
    for (int off = 1; off <= 32; off <<= 1) {
        const int t = __shfl_up(pre, off, 64);
        if (ln >= off) pre += t;
    }
    const int total = __shfl(pre, 63, 64);   // inclusive total = row degree
    int slot = pre - cnt;                    // exclusive prefix = lane's base
    while (bits) {
        const int bit = __ffs(bits) - 1;
        bits &= bits - 1;
        if (slot < CAPR) hits_l[wv][slot] = (unsigned short)(ln * 32 + bit);
        ++slot;
    }
    const int nh = min(total, CAPR);
    const int hv0 = hits_l[wv][ln];          // edges 0..63
    const int hv1 = hits_l[wv][64 + ln];     // edges 64..127

    const float* zb = z + ((size_t)b << 18);   // b*2048*128
    const float4* znp = (const float4*)(zb + ((size_t)n << 7) + (hq << 4));
    const float4 a0 = znp[0], a1 = znp[1], a2 = znp[2], a3 = znp[3];

    float m = NEG_INF, l = 0.f;
    float4 acc0 = make_float4(0.f, 0.f, 0.f, 0.f), acc1 = acc0, acc2 = acc0, acc3 = acc0;

#pragma unroll 2
    for (int c0 = 0; c0 < nh; c0 += 8) {
        const int e = c0 + eq;
        const int hv = (c0 < 64) ? hv0 : hv1;      // uniform select (c0 loop-scalar)
        const int he = __shfl(hv, e & 63, 64) & (NN - 1);   // edge id from registers
        const float4* zc = (const float4*)(zb + ((size_t)he << 7) + (hq << 4));
        const float4 v0 = zc[0], v1 = zc[1], v2 = zc[2], v3 = zc[3];
        float ch0 = a0.x * v0.x + a0.y * v0.y + a0.z * v0.z + a0.w * v0.w
                  + a1.x * v1.x + a1.y * v1.y + a1.z * v1.z + a1.w * v1.w;
        float ch1 = a2.x * v2.x + a2.y * v2.y + a2.z * v2.z + a2.w * v2.w
                  + a3.x * v3.x + a3.y * v3.y + a3.z * v3.z + a3.w * v3.w;
        float pt = ch0 + ch1;
        pt += __shfl_xor(pt, 1, 64);
        pt += __shfl_xor(pt, 2, 64);
        pt += __shfl_xor(pt, 4, 64);             // full 128-dim dot in all hq lanes
        float sv = pt > 0.f ? pt : LEAK * pt;    // leaky_relu(0.1)
        if (sv == 0.f || e >= nh) sv = NEG_INF;  // masked_fill(att==0) / pad

        if (__any(sv - m > THRS)) {              // defer-max rescale (rare)
            const float mnew = fmaxf(m, sv);
            const float alpha = __expf(m - mnew);
            m = mnew;
            l *= alpha;
            acc0.x *= alpha; acc0.y *= alpha; acc0.z *= alpha; acc0.w *= alpha;
            acc1.x *= alpha; acc1.y *= alpha; acc1.z *= alpha; acc1.w *= alpha;
            acc2.x *= alpha; acc2.y *= alpha; acc2.z *= alpha; acc2.w *= alpha;
            acc3.x *= alpha; acc3.y *= alpha; acc3.z *= alpha; acc3.w *= alpha;
        }
        const float pr = __expf(sv - m);         // exponent <= THRS, fp32-safe
        l += pr;
        acc0.x += pr * v0.x; acc0.y += pr * v0.y; acc0.z += pr * v0.z; acc0.w += pr * v0.w;
        acc1.x += pr * v1.x; acc1.y += pr * v1.y; acc1.z += pr * v1.z; acc1.w += pr * v1.w;
        acc2.x += pr * v2.x; acc2.y += pr * v2.y; acc2.z += pr * v2.z; acc2.w += pr * v2.w;
        acc3.x += pr * v3.x; acc3.y += pr * v3.y; acc3.z += pr * v3.z; acc3.w += pr * v3.w;
    }

    float M = m;
#pragma unroll
    for (int off = 8; off <= 32; off <<= 1) M = fmaxf(M, __shfl_xor(M, off, 64));

    if (nh > 0 && M > 0.5f * NEG_INF) {
        const float al = __expf(m - M);          // 0 for all-pad lanes
        l *= al;
        acc0.x *= al; acc0.y *= al; acc0.z *= al; acc0.w *= al;
        acc1.x *= al; acc1.y *= al; acc1.z *= al; acc1.w *= al;
        acc2.x *= al; acc2.y *= al; acc2.z *= al; acc2.w *= al;
        acc3.x *= al; acc3.y *= al; acc3.z *= al; acc3.w *= al;
#pragma unroll
        for (int off = 8; off <= 32; off <<= 1) {
            l += __shfl_xor(l, off, 64);
            acc0.x += __shfl_xor(acc0.x, off, 64); acc0.y += __shfl_xor(acc0.y, off, 64);
            acc0.z += __shfl_xor(acc0.z, off, 64); acc0.w += __shfl_xor(acc0.w, off, 64);
            acc1.x += __shfl_xor(acc1.x, off, 64); acc1.y += __shfl_xor(acc1.y, off, 64);
            acc1.z += __shfl_xor(acc1.z, off, 64); acc1.w += __shfl_xor(acc1.w, off, 64);
            acc2.x += __shfl_xor(acc2.x, off, 64); acc2.y += __shfl_xor(acc2.y, off, 64);
            acc2.z += __shfl_xor(acc2.z, off, 64); acc2.w += __shfl_xor(acc2.w, off, 64);
            acc3.x += __shfl_xor(acc3.x, off, 64); acc3.y += __shfl_xor(acc3.y, off, 64);
            acc3.z += __shfl_xor(acc3.z, off, 64); acc3.w += __shfl_xor(acc3.w, off, 64);
        }
        const float inv = 1.f / l;
        acc0.x *= inv; acc0.y *= inv; acc0.z *= inv; acc0.w *= inv;
        acc1.x *= inv; acc1.y *= inv; acc1.z *= inv; acc1.w *= inv;
        acc2.x *= inv; acc2.y *= inv; acc2.z *= inv; acc2.w *= inv;
        acc3.x *= inv; acc3.y *= inv; acc3.z *= inv; acc3.w *= inv;
    } else {
        // no valid edge: softmax over uniform -1e16 row -> mean of z[b]
        acc0 = make_float4(0.f, 0.f, 0.f, 0.f); acc1 = acc0; acc2 = acc0; acc3 = acc0;
        for (int mm = 0; mm < NN; ++mm) {
            const float4* zr = (const float4*)(zb + ((size_t)mm << 7) + (hq << 4));
            const float4 t0 = zr[0], t1 = zr[1], t2 = zr[2], t3 = zr[3];
            acc0.x += t0.x; acc0.y += t0.y; acc0.z += t0.z; acc0.w += t0.w;
            acc1.x += t1.x; acc1.y += t1.y; acc1.z += t1.z; acc1.w += t1.w;
            acc2.x += t2.x; acc2.y += t2.y; acc2.z += t2.z; acc2.w += t2.w;
            acc3.x += t3.x; acc3.y += t3.y; acc3.z += t3.z; acc3.w += t3.w;
        }
        const float s = 1.f / NN;
        acc0.x *= s; acc0.y *= s; acc0.z *= s; acc0.w *= s;
        acc1.x *= s; acc1.y *= s; acc1.z *= s; acc1.w *= s;
        acc2.x *= s; acc2.y *= s; acc2.z *= s; acc2.w *= s;
        acc3.x *= s; acc3.y *= s; acc3.z *= s; acc3.w *= s;
    }

    if (eq < 4) {
        float4 o = acc0;
        if (eq == 1) o = acc1;
        if (eq == 2) o = acc2;
        if (eq == 3) o = acc3;
        *(float4*)(out + (((size_t)b * NN + n) << 7) + (hq << 4) + (eq << 2)) = o;
    }
}

// ---------------- launcher ----------------
extern "C" void kernel_launch(void* const* d_in, const int* in_sizes, int n_in,
                              void* d_out, int out_size, void* d_ws, size_t ws_size,
                              hipStream_t stream) {
    const float* h = (const float*)d_in[0];
    const float* W = (const float*)d_in[1];
    const int* row = (const int*)d_in[2];
    const int* col = (const int*)d_in[3];
    float* out = (float*)d_out;

    char* ws = (char*)d_ws;
    float* z = (float*)ws;                                                     // 16 MB
    unsigned int* mask = (unsigned int*)(ws + (size_t)16 * 1024 * 1024);       // 512 KB
    unsigned short* Wp = (unsigned short*)(ws + (size_t)16 * 1024 * 1024 + 512 * 1024); // 64 KB

    hipMemsetAsync(mask, 0, (size_t)NN * NN / 8, stream);
    wprep_kernel<<<16, 256, 0, stream>>>(W, Wp);                      // ~2 us, once
    zedge_kernel<<<768, 256, 0, stream>>>(h, Wp, z, row, col, mask);  // 256 edge + 512 gemm
    gat_kernel<<<(BC * NN) / 4, 256, 0, stream>>>(z, mask, out);
}